// Round 7
// baseline (650.403 us; speedup 1.0000x reference)
//
#include <hip/hip_runtime.h>

// SparseAttention MI355X — round 7: r6 decoupled pipeline with the topk_pv
// bisection bug fixed (r6 float bisection left Thi stale on early break ->
// band overflow -> dropped true top-64 members -> absmax 0.331).
// Now: integer sortkey bisection to the EXACT approx-64th (r5-proven), margin
// band (MARGIN=1e-3 >= 2*err_max ~ 3.4e-4) + exact f64 rescore of the band.
//   A) score_gemm: S=QK^T/16 fp32 -> ws (LDS-staged split-bf16 3-pass MFMA)
//   B) vsum: per-batch V column sums (vlen==0 path)
//   C) topk_pv: 1 wave per q-row; exact top-64; softmax; coalesced V gather.
// Fallback to r5 fused kernel if ws_size < 128MB+8KB (r6 run proved ws is big enough).

#define QN 2048
#define KN 2048
#define DN 256
#define NEGV (-1000000.0f)
#define MARGIN 1e-3f
#define WS_NEED 134225920ull
#define BANDCAP 48

typedef __attribute__((ext_vector_type(8))) short short8;
typedef __attribute__((ext_vector_type(4))) float f32x4;

union U4S8 { uint4 u; short8 s; };

__device__ __forceinline__ unsigned sortkey(unsigned b) {
  return b ^ (unsigned)((((int)b) >> 31) | 0x80000000u);
}
__device__ __forceinline__ float keytofloat(unsigned k) {
  unsigned b = (k & 0x80000000u) ? (k ^ 0x80000000u) : ~k;
  return __uint_as_float(b);
}
__device__ __forceinline__ unsigned long long sortkey64(double d) {
  long long b = __double_as_longlong(d);
  return (unsigned long long)(b ^ ((b >> 63) | 0x8000000000000000LL));
}
__device__ __forceinline__ unsigned pack_hi(unsigned a, unsigned b) {
  return (b & 0xFFFF0000u) | (a >> 16);
}

__device__ __forceinline__ void split8(const float4& x0, const float4& x1,
                                       short8& hi8, short8& lo8) {
  float f[8] = {x0.x, x0.y, x0.z, x0.w, x1.x, x1.y, x1.z, x1.w};
  unsigned hw[4], lw[4];
#pragma unroll
  for (int i = 0; i < 4; ++i) {
    unsigned a = __float_as_uint(f[2 * i]);
    unsigned b = __float_as_uint(f[2 * i + 1]);
    hw[i] = pack_hi(a, b);
    float ra = f[2 * i]     - __uint_as_float(a & 0xFFFF0000u);
    float rb = f[2 * i + 1] - __uint_as_float(b & 0xFFFF0000u);
    lw[i] = pack_hi(__float_as_uint(ra), __float_as_uint(rb));
  }
  U4S8 h, l;
  h.u = make_uint4(hw[0], hw[1], hw[2], hw[3]);
  l.u = make_uint4(lw[0], lw[1], lw[2], lw[3]);
  hi8 = h.s;
  lo8 = l.s;
}

__device__ __forceinline__ void split4(const float4& x, uint2& hu, uint2& lu) {
  unsigned a0 = __float_as_uint(x.x), a1 = __float_as_uint(x.y);
  unsigned a2 = __float_as_uint(x.z), a3 = __float_as_uint(x.w);
  hu.x = pack_hi(a0, a1);
  hu.y = pack_hi(a2, a3);
  float r0 = x.x - __uint_as_float(a0 & 0xFFFF0000u);
  float r1 = x.y - __uint_as_float(a1 & 0xFFFF0000u);
  float r2 = x.z - __uint_as_float(a2 & 0xFFFF0000u);
  float r3 = x.w - __uint_as_float(a3 & 0xFFFF0000u);
  lu.x = pack_hi(__float_as_uint(r0), __float_as_uint(r1));
  lu.y = pack_hi(__float_as_uint(r2), __float_as_uint(r3));
}

// =================== A: score GEMM  S[b][q][k] = (Q.K^T)/16 ===================
__global__ __launch_bounds__(256) void score_gemm(const float* __restrict__ Q,
                                                  const float* __restrict__ K,
                                                  const int* __restrict__ vlens,
                                                  float* __restrict__ S) {
  __shared__ unsigned short KT[128][64];  // 16 KB: [col][hi 32 | lo 32], XOR-swizzled

  const unsigned tid = threadIdx.x;
  const unsigned w = tid >> 6, lane = tid & 63u;
  const unsigned lm = lane & 15u, lg = lane >> 4;
  const unsigned bid = blockIdx.x;
  const unsigned b = bid >> 9;
  const unsigned r9 = bid & 511u;
  const unsigned ct = r9 >> 5, qt = r9 & 31u;  // qt fastest: K-tile L2 reuse
  const int vlen = vlens[b];
  const unsigned colbase = ct * 128u;
  if ((int)colbase >= vlen) return;

  // Q fragments for this wave's 16 rows (hi/lo split)
  short8 qh[8], ql[8];
  const float* qrow = Q + ((size_t)(b * QN + qt * 64u + w * 16u + lm)) * DN;
#pragma unroll
  for (int c = 0; c < 8; ++c) {
    float4 x0 = *(const float4*)(qrow + c * 32 + lg * 8);
    float4 x1 = *(const float4*)(qrow + c * 32 + lg * 8 + 4);
    split8(x0, x1, qh[c], ql[c]);
  }

  f32x4 acc[8];
#pragma unroll
  for (int j = 0; j < 8; ++j) acc[j] = (f32x4){0.f, 0.f, 0.f, 0.f};

  for (unsigned c = 0; c < 8; ++c) {
    __syncthreads();
    // stage K[colbase..+128][c*32..+32] -> hi/lo bf16 in LDS (coalesced 128B rows)
#pragma unroll
    for (int i = 0; i < 4; ++i) {
      unsigned col = (tid >> 3) + i * 32u;
      unsigned gi = (tid >> 1) & 3u;
      unsigned h2 = tid & 1u;
      const float4 v = *(const float4*)(K + ((size_t)(b * KN + colbase + col)) * DN +
                                        c * 32u + gi * 8u + h2 * 4u);
      uint2 hu, lu;
      split4(v, hu, lu);
      unsigned slot = gi ^ (col & 3u);
      *(uint2*)&KT[col][slot * 8u + h2 * 4u] = hu;
      *(uint2*)&KT[col][32u + slot * 8u + h2 * 4u] = lu;
    }
    __syncthreads();
#pragma unroll
    for (int j = 0; j < 8; ++j) {
      unsigned col = j * 16u + lm;
      unsigned slot = lg ^ (col & 3u);
      short8 kh = *(const short8*)&KT[col][slot * 8u];
      short8 kl = *(const short8*)&KT[col][32u + slot * 8u];
      acc[j] = __builtin_amdgcn_mfma_f32_16x16x32_bf16(qh[c], kh, acc[j], 0, 0, 0);
      acc[j] = __builtin_amdgcn_mfma_f32_16x16x32_bf16(ql[c], kh, acc[j], 0, 0, 0);
      acc[j] = __builtin_amdgcn_mfma_f32_16x16x32_bf16(qh[c], kl, acc[j], 0, 0, 0);
    }
  }

  float* Sb = S + ((size_t)b * QN + qt * 64u + w * 16u) * (size_t)KN + colbase;
#pragma unroll
  for (int j = 0; j < 8; ++j)
#pragma unroll
    for (int r = 0; r < 4; ++r)
      Sb[(size_t)(lg * 4u + r) * KN + j * 16u + lm] = acc[j][r] * 0.0625f;
}

// =================== B: per-batch V column sums ===================
__global__ __launch_bounds__(256) void vsum_kernel(const float* __restrict__ V,
                                                   float* __restrict__ vsum) {
  __shared__ float red[8][32];
  unsigned b = blockIdx.x >> 3, chunk = blockIdx.x & 7u;
  unsigned c = threadIdx.x & 31u, s = threadIdx.x >> 5;
  unsigned col = chunk * 32u + c;
  const float* base = V + ((size_t)b * KN + s * 256u) * DN + col;
  float acc = 0.f;
#pragma unroll 8
  for (int r = 0; r < 256; ++r) acc += base[(size_t)r * DN];
  red[s][c] = acc;
  __syncthreads();
  if (s == 0) {
    float t = 0.f;
#pragma unroll
    for (int j = 0; j < 8; ++j) t += red[j][c];
    vsum[b * DN + col] = t;
  }
}

// =================== C: top-64 + softmax + V gather (1 wave / row) ===================
__global__ __launch_bounds__(256) void topk_pv(const float* __restrict__ Q,
                                               const float* __restrict__ K,
                                               const float* __restrict__ V,
                                               const int* __restrict__ vlens,
                                               const float* __restrict__ S,
                                               const float* __restrict__ vsum,
                                               float* __restrict__ out) {
  __shared__ uint2 selbuf[4][64];
  __shared__ unsigned long long bkey[4][BANDCAP];
  __shared__ unsigned bcol[4][BANDCAP];
  __shared__ unsigned char bpicked[4][BANDCAP];

  const unsigned tid = threadIdx.x, w = tid >> 6, lane = tid & 63u;
  const size_t row = (size_t)blockIdx.x * 4u + w;
  const unsigned b = (unsigned)(row >> 11);
  const int vlen = vlens[b];
  float* orow = out + row * DN;
  const unsigned long long below = (1ull << lane) - 1ull;

  if (vlen == 0) {
    const float4 sv = *(const float4*)(vsum + (size_t)b * DN + lane * 4u);
    const float cc = 1.0f / 2048.0f;
    *(float4*)(orow + lane * 4u) = make_float4(sv.x * cc, sv.y * cc, sv.z * cc, sv.w * cc);
    return;
  }

  // load this row's 2048 scores; col(k) = (k>>2)*256 + lane*4 + (k&3)
  const float* Srow = S + row * (size_t)KN;
  float v[32];
#pragma unroll
  for (int i = 0; i < 8; ++i) {
    float4 x = *(const float4*)(Srow + i * 256u + lane * 4u);
    int c0 = i * 256 + (int)lane * 4;
    v[i * 4 + 0] = (c0 + 0 < vlen) ? x.x : -3.4e38f;
    v[i * 4 + 1] = (c0 + 1 < vlen) ? x.y : -3.4e38f;
    v[i * 4 + 2] = (c0 + 2 < vlen) ? x.z : -3.4e38f;
    v[i * 4 + 3] = (c0 + 3 < vlen) ? x.w : -3.4e38f;
  }

  unsigned selm = 0u;
  if (vlen <= 64) {
#pragma unroll
    for (int k = 0; k < 32; ++k)
      if (v[k] > -1e30f) selm |= (1u << k);
  } else {
    // integer sortkey bisection -> EXACT approx-64th value (r5-proven)
    unsigned key[32];
#pragma unroll
    for (int k = 0; k < 32; ++k) key[k] = sortkey(__float_as_uint(v[k]));
    unsigned lo = 0u, hi = 0xFFFFFFF0u;
    for (int it = 0; it < 34 && lo < hi; ++it) {
      unsigned mid = lo + ((hi - lo + 1u) >> 1);
      int c = 0;
#pragma unroll
      for (int k = 0; k < 32; ++k)
        c += (int)__popcll(__ballot(key[k] >= mid));
      if (c == 64) { lo = mid; break; }
      if (c > 64) lo = mid; else hi = mid - 1u;
    }
    float m64f = keytofloat(lo);
    float hi_thr = m64f + MARGIN;   // definitely in true top-64 (M >= 2*err_max)
    float lo_thr = m64f - MARGIN;   // candidate floor (true top-64 superset)

    unsigned defm = 0u, bandm = 0u;
    int ndef = 0;
#pragma unroll
    for (int k = 0; k < 32; ++k) {
      bool d = v[k] >= hi_thr;
      bool bd = !d && (v[k] >= lo_thr);
      if (d) defm |= (1u << k);
      if (bd) bandm |= (1u << k);
      ndef += (int)d;
    }
#pragma unroll
    for (int off = 32; off > 0; off >>= 1) ndef += __shfl_xor(ndef, off);

    // exact f64 rescore of the boundary band (cooperative 64-lane dot)
    const float4 qv = *(const float4*)(Q + ((size_t)b * QN + (unsigned)(row & 2047u)) * DN + lane * 4u);
    const float* Kb = K + (size_t)b * KN * DN;
    int nb = 0;
#pragma unroll
    for (int k = 0; k < 32; ++k) {
      unsigned long long mk = __ballot((bandm >> k) & 1u);
      while (mk && nb < BANDCAP) {
        int src = __ffsll(mk) - 1;
        mk &= mk - 1ull;
        unsigned col = ((unsigned)(k >> 2)) * 256u + (unsigned)src * 4u + (unsigned)(k & 3);
        const float4 kv = *(const float4*)(Kb + (size_t)col * DN + lane * 4u);
        double s = fma((double)qv.x, (double)kv.x,
                   fma((double)qv.y, (double)kv.y,
                   fma((double)qv.z, (double)kv.z,
                       (double)qv.w * (double)kv.w)));
#pragma unroll
        for (int off = 32; off > 0; off >>= 1) s += __shfl_xor(s, off);
        if (lane == 0) {
          bkey[w][nb] = sortkey64(s * 0.0625);
          bcol[w][nb] = col;
          bpicked[w][nb] = 0;
        }
        ++nb;
      }
    }

    selm = defm;
    int need = 64 - ndef;
    for (int pi = 0; pi < need; ++pi) {
      unsigned long long best = 0ull;
      int bj = -1;
      for (int j2 = 0; j2 < nb; ++j2)
        if (!bpicked[w][j2] && bkey[w][j2] > best) { best = bkey[w][j2]; bj = j2; }
      if (bj < 0) break;
      if (lane == 0) bpicked[w][bj] = 1;
      unsigned col = bcol[w][bj];
      unsigned owner = (col >> 2) & 63u;
      unsigned kreg = ((col >> 8) << 2) | (col & 3u);
      if (lane == owner) selm |= (1u << kreg);
    }
  }

  // softmax over selected; compact (weight,col) into LDS
  float mx = -3.4e38f;
#pragma unroll
  for (int k = 0; k < 32; ++k)
    if ((selm >> k) & 1u) mx = fmaxf(mx, v[k]);
#pragma unroll
  for (int off = 32; off > 0; off >>= 1) mx = fmaxf(mx, __shfl_xor(mx, off));

  float zs = 0.f;
  unsigned base = 0;
#pragma unroll
  for (int k = 0; k < 32; ++k) {
    bool s1 = (selm >> k) & 1u;
    unsigned long long mk = __ballot(s1);
    float wt = s1 ? __expf(v[k] - mx) : 0.f;
    zs += wt;
    if (s1) {
      unsigned pos = base + (unsigned)__popcll(mk & below);
      unsigned col = ((unsigned)(k >> 2)) * 256u + lane * 4u + (unsigned)(k & 3);
      selbuf[w][pos] = make_uint2(__float_as_uint(wt), col);
    }
    base += (unsigned)__popcll(mk);
  }
#pragma unroll
  for (int off = 32; off > 0; off >>= 1) zs += __shfl_xor(zs, off);
  unsigned nsel = base;

  // V gather: full-wave coalesced 1KB row reads
  float4 a = make_float4(0.f, 0.f, 0.f, 0.f);
  const float* Vb = V + (size_t)b * KN * DN;
  for (unsigned e = 0; e < nsel; ++e) {
    uint2 pe = selbuf[w][e];
    float wt = __uint_as_float(pe.x);
    const float4 vv = *(const float4*)(Vb + (size_t)pe.y * DN + lane * 4u);
    a.x = fmaf(wt, vv.x, a.x);
    a.y = fmaf(wt, vv.y, a.y);
    a.z = fmaf(wt, vv.z, a.z);
    a.w = fmaf(wt, vv.w, a.w);
  }
  float rz = 1.0f / zs;
  *(float4*)(orow + lane * 4u) = make_float4(a.x * rz, a.y * rz, a.z * rz, a.w * rz);
}

// =================== fallback: r5 fused kernel (proven correct, 477us) ===================
#define PC 128
#define CAP 200u
#define CAPP 201
#define TRIG 72u
#define FMARGIN 3e-4f

__global__ __launch_bounds__(256, 2) void sparse_attn_fused(const float* __restrict__ Q,
                                                            const float* __restrict__ K,
                                                            const float* __restrict__ V,
                                                            const int* __restrict__ vlens,
                                                            float* __restrict__ out) {
  __shared__ float Sm[32][PC];
  __shared__ uint2 pool[32][CAPP];
  __shared__ unsigned cnt[32];
  __shared__ unsigned Lb[32];
  __shared__ unsigned nqs[32];
  __shared__ float rden[32];

  const unsigned tid = threadIdx.x;
  const unsigned w = tid >> 6, lane = tid & 63u;
  const unsigned lm = lane & 15u, lg = lane >> 4;
  const unsigned bid = blockIdx.x;
  const unsigned b = bid >> 6, qt = bid & 63u;
  const int vlen = vlens[b];
  const unsigned long long below = (1ull << lane) - 1ull;

  if (vlen == 0) {
    float* PS = (float*)&pool[0][0];
    unsigned g = tid >> 3, ds = tid & 7u;
    float4 s[8];
#pragma unroll
    for (int j = 0; j < 8; ++j) s[j] = make_float4(0.f, 0.f, 0.f, 0.f);
    const float* Vb = V + (size_t)b * KN * DN;
    for (int i = 0; i < 64; ++i) {
      const float* vr = Vb + (size_t)(g * 64u + i) * DN + ds * 32u;
#pragma unroll
      for (int j = 0; j < 8; ++j) {
        float4 vv = *(const float4*)(vr + j * 4);
        s[j].x += vv.x; s[j].y += vv.y; s[j].z += vv.z; s[j].w += vv.w;
      }
    }
#pragma unroll
    for (int j = 0; j < 8; ++j)
      *(float4*)&PS[g * 256u + ds * 32u + j * 4] = s[j];
    __syncthreads();
    float mval = 0.f;
    for (int g2 = 0; g2 < 32; ++g2) mval += PS[g2 * 256 + tid];
    PS[8192 + tid] = mval * (1.0f / 2048.0f);
    __syncthreads();
    unsigned row = tid >> 3;
    float* op = out + ((size_t)(b * QN + qt * 32u + row)) * DN + ds * 32u;
#pragma unroll
    for (int j = 0; j < 8; ++j)
      *(float4*)(op + j * 4) = *(const float4*)&PS[8192 + ds * 32u + j * 4];
    return;
  }

  if (tid < 32) { cnt[tid] = 0u; Lb[tid] = 0u; }
  __syncthreads();

  short8 qh[2][8], ql[2][8];
#pragma unroll
  for (int rt = 0; rt < 2; ++rt) {
    const float* qrow = Q + ((size_t)(b * QN + qt * 32u + rt * 16u + lm)) * DN;
#pragma unroll
    for (int c = 0; c < 8; ++c) {
      const float* src = qrow + c * 32u + lg * 8u;
      float4 x0 = *(const float4*)(src);
      float4 x1 = *(const float4*)(src + 4);
      split8(x0, x1, qh[rt][c], ql[rt][c]);
    }
  }

  const float* Kb = K + (size_t)b * KN * DN;
  unsigned nparts = ((unsigned)vlen + (PC - 1)) / PC;
  if (nparts > 16u) nparts = 16u;

  for (unsigned p = 0; p < nparts; ++p) {
    f32x4 acc[2][2];
#pragma unroll
    for (int rt = 0; rt < 2; ++rt)
#pragma unroll
      for (int j = 0; j < 2; ++j) acc[rt][j] = (f32x4){0.f, 0.f, 0.f, 0.f};

    unsigned colbase = p * PC + w * 32u;
#pragma unroll
    for (int c = 0; c < 8; ++c) {
#pragma unroll
      for (int j = 0; j < 2; ++j) {
        const float* src = Kb + (size_t)(colbase + j * 16u + lm) * DN + c * 32u + lg * 8u;
        float4 x0 = *(const float4*)(src);
        float4 x1 = *(const float4*)(src + 4);
        short8 kh, kl;
        split8(x0, x1, kh, kl);
        acc[0][j] = __builtin_amdgcn_mfma_f32_16x16x32_bf16(qh[0][c], kh, acc[0][j], 0, 0, 0);
        acc[1][j] = __builtin_amdgcn_mfma_f32_16x16x32_bf16(qh[1][c], kh, acc[1][j], 0, 0, 0);
        acc[0][j] = __builtin_amdgcn_mfma_f32_16x16x32_bf16(ql[0][c], kh, acc[0][j], 0, 0, 0);
        acc[1][j] = __builtin_amdgcn_mfma_f32_16x16x32_bf16(ql[1][c], kh, acc[1][j], 0, 0, 0);
        acc[0][j] = __builtin_amdgcn_mfma_f32_16x16x32_bf16(qh[0][c], kl, acc[0][j], 0, 0, 0);
        acc[1][j] = __builtin_amdgcn_mfma_f32_16x16x32_bf16(qh[1][c], kl, acc[1][j], 0, 0, 0);
      }
    }

#pragma unroll
    for (int rt = 0; rt < 2; ++rt)
#pragma unroll
      for (int j = 0; j < 2; ++j)
#pragma unroll
        for (int r = 0; r < 4; ++r) {
          unsigned rrow = rt * 16u + lg * 4u + r;
          unsigned col = w * 32u + j * 16u + lm;
          float vv = acc[rt][j][r] * 0.0625f;
          if (p * PC + col >= (unsigned)vlen) vv = NEGV;
          Sm[rrow][col] = vv;
        }
    __syncthreads();

    for (int rr = 0; rr < 8; ++rr) {
      unsigned row = w * 8u + rr;
      unsigned L = Lb[row];
#pragma unroll
      for (int i = 0; i < 2; ++i) {
        unsigned cidx = lane + 64u * i;
        float vv = Sm[row][cidx];
        unsigned kk = sortkey(__float_as_uint(vv));
        bool qual = (vv != NEGV) && (kk >= L);
        unsigned long long mask = __ballot(qual);
        if (mask) {
          int ldr = __ffsll((unsigned long long)mask) - 1;
          unsigned bse = 0;
          if ((int)lane == ldr) bse = atomicAdd(&cnt[row], (unsigned)__popcll(mask));
          bse = __shfl(bse, ldr);
          unsigned pos = bse + (unsigned)__popcll(mask & below);
          if (qual && pos < CAP)
            pool[row][pos] = make_uint2(__float_as_uint(vv), p * PC + cidx);
        }
      }
      unsigned n = cnt[row]; if (n > CAP) n = CAP;
      if (n > TRIG) {
        bool val[4]; uint2 e[4]; unsigned key[4]; float f[4];
#pragma unroll
        for (int t = 0; t < 4; ++t) {
          unsigned idx = lane + 64u * t;
          val[t] = idx < n;
          e[t] = val[t] ? pool[row][idx] : make_uint2(0u, 0u);
          key[t] = val[t] ? sortkey(e[t].x) : 0u;
          f[t] = val[t] ? __uint_as_float(e[t].x) : -3.4e38f;
        }
        unsigned lo = 0u, hi = 0xFFFFFFF0u;
        for (int it = 0; it < 34 && lo < hi; ++it) {
          unsigned mid = lo + ((hi - lo + 1u) >> 1);
          int c = 0;
#pragma unroll
          for (int t = 0; t < 4; ++t) c += (int)__popcll(__ballot(key[t] >= mid));
          if (c == 64) { lo = mid; break; }
          if (c > 64) lo = mid; else hi = mid - 1u;
        }
        float thrf = keytofloat(lo) - FMARGIN;
        unsigned nn = 0;
#pragma unroll
        for (int t = 0; t < 4; ++t) {
          bool q = val[t] && (f[t] >= thrf);
          unsigned long long mk = __ballot(q);
          if (q) pool[row][nn + (unsigned)__popcll(mk & below)] = e[t];
          nn += (unsigned)__popcll(mk);
        }
        if (lane == 0) { cnt[row] = nn; Lb[row] = sortkey(__float_as_uint(thrf)); }
      }
    }
    __syncthreads();
  }

  for (int rr = 0; rr < 8; ++rr) {
    unsigned row = w * 8u + rr;
    unsigned n = cnt[row]; if (n > CAP) n = CAP;
    bool val[4]; uint2 e[4]; unsigned key[4]; float f[4];
#pragma unroll
    for (int t = 0; t < 4; ++t) {
      unsigned idx = lane + 64u * t;
      val[t] = idx < n;
      e[t] = val[t] ? pool[row][idx] : make_uint2(0u, 0u);
      key[t] = val[t] ? sortkey(e[t].x) : 0u;
      f[t] = val[t] ? __uint_as_float(e[t].x) : -3.4e38f;
    }
    bool sel[4];
    if (n > 64u) {
      unsigned lo = 0u, hi = 0xFFFFFFF0u;
      for (int it = 0; it < 34 && lo < hi; ++it) {
        unsigned mid = lo + ((hi - lo + 1u) >> 1);
        int c = 0;
#pragma unroll
        for (int t = 0; t < 4; ++t) c += (int)__popcll(__ballot(key[t] >= mid));
        if (c == 64) { lo = mid; break; }
        if (c > 64) lo = mid; else hi = mid - 1u;
      }
      float m64f = keytofloat(lo);
      float hi_thr = m64f + FMARGIN, lo_thr = m64f - FMARGIN;
      bool def_[4], band[4];
      int ndef = 0;
#pragma unroll
      for (int t = 0; t < 4; ++t) {
        def_[t] = val[t] && (f[t] >= hi_thr);
        band[t] = val[t] && !def_[t] && (f[t] >= lo_thr);
        ndef += (int)__popcll(__ballot(def_[t]));
      }
      const float* qrow = Q + ((size_t)(b * QN + qt * 32u + row)) * DN;
      float4 qv = *(const float4*)(qrow + lane * 4u);
      unsigned long long K64[4] = {0ull, 0ull, 0ull, 0ull};
#pragma unroll
      for (int t = 0; t < 4; ++t) {
        unsigned long long mk = __ballot(band[t]);
        while (mk) {
          int src = __ffsll(mk) - 1;
          mk &= mk - 1ull;
          unsigned col = (unsigned)__shfl((int)e[t].y, src);
          const float4 kv = *(const float4*)(Kb + (size_t)col * DN + lane * 4u);
          double s = fma((double)qv.x, (double)kv.x,
                     fma((double)qv.y, (double)kv.y,
                     fma((double)qv.z, (double)kv.z,
                         (double)qv.w * (double)kv.w)));
#pragma unroll
          for (int off = 32; off > 0; off >>= 1) s += __shfl_xor(s, off);
          if ((int)lane == src) K64[t] = sortkey64(s * 0.0625);
        }
      }
      bool rem[4];
#pragma unroll
      for (int t = 0; t < 4; ++t) { sel[t] = def_[t]; rem[t] = band[t]; }
      int sc = ndef;
      while (sc < 64) {
        unsigned long long mv = 0ull;
#pragma unroll
        for (int t = 0; t < 4; ++t)
          if (rem[t] && K64[t] > mv) mv = K64[t];
#pragma unroll
        for (int off = 32; off > 0; off >>= 1) {
          unsigned long long o = __shfl_xor(mv, off);
          if (o > mv) mv = o;
        }
        bool picked = false;
#pragma unroll
        for (int t = 0; t < 4; ++t) {
          if (!picked) {
            unsigned long long mk = __ballot(rem[t] && K64[t] == mv);
            if (mk) {
              if ((int)lane == __ffsll(mk) - 1) { rem[t] = false; sel[t] = true; }
              picked = true;
            }
          }
        }
        ++sc;
        if (!picked) break;
      }
    } else {
#pragma unroll
      for (int t = 0; t < 4; ++t) sel[t] = val[t];
    }

    float mv2 = -3.4e38f;
#pragma unroll
    for (int t = 0; t < 4; ++t) if (val[t]) mv2 = fmaxf(mv2, f[t]);
#pragma unroll
    for (int off = 32; off > 0; off >>= 1) mv2 = fmaxf(mv2, __shfl_xor(mv2, off));

    bool q0 = sel[0], q1 = sel[1], q2 = sel[2], q3 = sel[3];
    float w0 = q0 ? __expf(f[0] - mv2) : 0.f;
    float w1 = q1 ? __expf(f[1] - mv2) : 0.f;
    float w2 = q2 ? __expf(f[2] - mv2) : 0.f;
    float w3 = q3 ? __expf(f[3] - mv2) : 0.f;
    float ws2 = w0 + w1 + w2 + w3;
#pragma unroll
    for (int off = 32; off > 0; off >>= 1) ws2 += __shfl_xor(ws2, off);

    unsigned nn = 0;
    {
      unsigned long long mk = __ballot(q0);
      if (q0) pool[row][nn + (unsigned)__popcll(mk & below)] = make_uint2(__float_as_uint(w0), e[0].y);
      nn += (unsigned)__popcll(mk);
      mk = __ballot(q1);
      if (q1) pool[row][nn + (unsigned)__popcll(mk & below)] = make_uint2(__float_as_uint(w1), e[1].y);
      nn += (unsigned)__popcll(mk);
      mk = __ballot(q2);
      if (q2) pool[row][nn + (unsigned)__popcll(mk & below)] = make_uint2(__float_as_uint(w2), e[2].y);
      nn += (unsigned)__popcll(mk);
      mk = __ballot(q3);
      if (q3) pool[row][nn + (unsigned)__popcll(mk & below)] = make_uint2(__float_as_uint(w3), e[3].y);
      nn += (unsigned)__popcll(mk);
    }
    if (lane == 0) { nqs[row] = nn; rden[row] = 1.0f / ws2; }
  }
  __syncthreads();

  {
    unsigned grow = tid >> 3, gds = tid & 7u;
    unsigned gnq = nqs[grow];
    float rd = rden[grow];
    float4 a[8];
#pragma unroll
    for (int j = 0; j < 8; ++j) a[j] = make_float4(0.f, 0.f, 0.f, 0.f);
    const float* Vb = V + (size_t)b * KN * DN;
    for (unsigned ei = 0; ei < gnq; ++ei) {
      uint2 pe = pool[grow][ei];
      float wvv = __uint_as_float(pe.x);
      const float* vr = Vb + (size_t)pe.y * DN + gds * 32u;
#pragma unroll
      for (int j = 0; j < 8; ++j) {
        float4 vv = *(const float4*)(vr + j * 4);
        a[j].x = fmaf(wvv, vv.x, a[j].x);
        a[j].y = fmaf(wvv, vv.y, a[j].y);
        a[j].z = fmaf(wvv, vv.z, a[j].z);
        a[j].w = fmaf(wvv, vv.w, a[j].w);
      }
    }
    float* op = out + ((size_t)(b * QN + qt * 32u + grow)) * DN + gds * 32u;
#pragma unroll
    for (int j = 0; j < 8; ++j) {
      float4 r = make_float4(a[j].x * rd, a[j].y * rd, a[j].z * rd, a[j].w * rd);
      *(float4*)(op + j * 4) = r;
    }
  }
}

extern "C" void kernel_launch(void* const* d_in, const int* in_sizes, int n_in,
                              void* d_out, int out_size, void* d_ws, size_t ws_size,
                              hipStream_t stream) {
  (void)in_sizes; (void)n_in; (void)out_size;
  const float* Q = (const float*)d_in[0];
  const float* K = (const float*)d_in[1];
  const float* V = (const float*)d_in[2];
  const int* vl = (const int*)d_in[3];
  float* out = (float*)d_out;

  if (ws_size >= WS_NEED) {
    float* S = (float*)d_ws;
    float* vsum = (float*)((char*)d_ws + 134217728ull);
    score_gemm<<<dim3(4096), dim3(256), 0, stream>>>(Q, K, vl, S);
    vsum_kernel<<<dim3(64), dim3(256), 0, stream>>>(V, vsum);
    topk_pv<<<dim3(4096), dim3(256), 0, stream>>>(Q, K, V, vl, S, vsum, out);
  } else {
    sparse_attn_fused<<<dim3(512), dim3(256), 0, stream>>>(Q, K, V, vl, out);
  }
}